// Round 14
// baseline (54.859 us; speedup 1.0000x reference)
//
#include <hip/hip_runtime.h>

// Problem dims: B=2, b=16, t_q=64, t_k=128, d=512, slices = 32
// d_out = context [32][64][512] f32 ++ scores_normalized [32][64][128] f32
// d_ws: pqT [32][512][64] (4MB) ++ pkT [32][512][128] (8MB)
// Two kernels only: proj stages f32 directly (in-register f16 convert after
// ds_read — identical RTZ numerics to the old cvt pass), score reads vatt raw.

#define DEV_INLINE __device__ __forceinline__

constexpr float C2    = 2.8853900817779268f;  // 2*log2(e)
constexpr float LOG2E = 1.4426950408889634f;

typedef _Float16 f16x8 __attribute__((ext_vector_type(8)));
typedef float    f32x16 __attribute__((ext_vector_type(16)));

DEV_INLINE unsigned int pk2(float a, float b) {
    auto h = __builtin_amdgcn_cvt_pkrtz(a, b);
    return __builtin_bit_cast(unsigned int, h);
}

DEV_INLINE f16x8 mkfrag(float4 c0, float4 c1) {   // 8 f32 -> 8 f16 (RTZ)
    uint4 u;
    u.x = pk2(c0.x, c0.y); u.y = pk2(c0.z, c0.w);
    u.z = pk2(c1.x, c1.y); u.w = pk2(c1.z, c1.w);
    return __builtin_bit_cast(f16x8, u);
}

// Newton reciprocal: pure-VALU replacement for v_rcp_f32 (rel err ~6e-6)
DEV_INLINE float rcp_nr(float d) {
    float y = __builtin_bit_cast(float, 0x7EF311C3u - __builtin_bit_cast(unsigned int, d));
    y = y * (2.0f - d * y);
    y = y * (2.0f - d * y);
    return y;
}

#define GL2LDS16(g, l) __builtin_amdgcn_global_load_lds( \
    (const __attribute__((address_space(1))) void*)(g),  \
    (__attribute__((address_space(3))) void*)(l), 16, 0, 0)

DEV_INLINE float wave_rsum(float v) {
#pragma unroll
    for (int off = 32; off; off >>= 1) v += __shfl_xor(v, off, 64);
    return v;
}
DEV_INLINE float wave_rmax(float v) {
#pragma unroll
    for (int off = 32; off; off >>= 1) v = fmaxf(v, __shfl_xor(v, off, 64));
    return v;
}

// ---------------------------------------------------------------------------
// fp16 MFMA projection GEMM, f32 direct staging (no cvt pass).
// Y[slice][n][t] = C2 * dot(X[t-row], W[n-row]).  A = W (128 n), B = X (64 t).
// LDS per buf: A[128 rows][8 slots x 16B f32] 16KB + B[64][8] 8KB; dbuf 48KB.
// Swizzle: slot ^= row&7 (f32 row = 128B = full bank period), applied on the
// pre-swizzled GLOBAL source (linear LDS dest) + the ds_read side (rule #21).
// Fragments converted f32->f16 in-register (same RTZ values as old cvt pass).
// Blocks 0..127: query (TK=64). 128..383: keys (TK=128).
// ---------------------------------------------------------------------------
__global__ __launch_bounds__(256)
void proj_mfma_kernel(const float* __restrict__ query, const float* __restrict__ keys,
                      const float* __restrict__ Wq,    const float* __restrict__ Wk,
                      float* __restrict__ pqT,         float* __restrict__ pkT)
{
    __shared__ __align__(16) unsigned char smem[49152];   // 2 x (A 16KB + B 8KB)

    // bijective chunked XCD swizzle (384 % 8 == 0)
    const int bid = (blockIdx.x & 7) * 48 + (blockIdx.x >> 3);

    int Bi, mt, tt, tkshift;
    const float *Ab, *Bb; float* Y;
    if (bid < 128) {      // query GEMM
        Bi = bid >> 6; mt = (bid >> 4) & 3; tt = bid & 15;
        Bb = query + ((size_t)Bi * 1024 + tt * 64) * 512;
        Ab = Wq + (size_t)Bi * 262144 + (size_t)(mt * 128) * 512;
        Y = pqT; tkshift = 6;
    } else {              // keys GEMM
        const int b2 = bid - 128;
        Bi = b2 >> 7; mt = (b2 >> 5) & 3; tt = b2 & 31;
        Bb = keys + ((size_t)Bi * 2048 + tt * 64) * 512;
        Ab = Wk + (size_t)Bi * 262144 + (size_t)(mt * 128) * 512;
        Y = pkT; tkshift = 7;
    }
    const int tid = threadIdx.x;

    // staging: linear LDS slot u -> pre-swizzled global source
    auto srcoff = [](int u) {
        const int row = u >> 3, s = (u & 7) ^ (row & 7);
        return (size_t)row * 512 + s * 4;
    };
    const float* gA0 = Ab + srcoff(tid);          // A rows  0..31
    const float* gA1 = Ab + srcoff(tid + 256);    // A rows 32..63
    const float* gA2 = Ab + srcoff(tid + 512);    // A rows 64..95
    const float* gA3 = Ab + srcoff(tid + 768);    // A rows 96..127
    const float* gB0 = Bb + srcoff(tid);          // B rows  0..31
    const float* gB1 = Bb + srcoff(tid + 256);    // B rows 32..63
    unsigned char* const lA0 = smem + tid * 16;
    unsigned char* const lA1 = smem + 4096  + tid * 16;
    unsigned char* const lA2 = smem + 8192  + tid * 16;
    unsigned char* const lA3 = smem + 12288 + tid * 16;
    unsigned char* const lB0 = smem + 16384 + tid * 16;
    unsigned char* const lB1 = smem + 20480 + tid * 16;

    // wave decomposition / fragment read offsets
    const int wid = tid >> 6, lane = tid & 63;
    const int wm = wid >> 1, wn = wid & 1;
    const int r31 = lane & 31, h = lane >> 5;
    auto lofs = [](int row, int slot) {
        return row * 128 + ((slot ^ (row & 7)) * 16);
    };
    const int rowA0 = wm * 64 + r31, rowA1 = rowA0 + 32, rowB = wn * 32 + r31;
    // frag (K-half kh, lane-half h) covers k-group g = 2*kh + h -> slots {2g, 2g+1}
    const int a00_0 = lofs(rowA0, 2 * h),     a00_1 = lofs(rowA0, 2 * h + 1);
    const int a01_0 = lofs(rowA0, 4 + 2 * h), a01_1 = lofs(rowA0, 5 + 2 * h);
    const int a10_0 = lofs(rowA1, 2 * h),     a10_1 = lofs(rowA1, 2 * h + 1);
    const int a11_0 = lofs(rowA1, 4 + 2 * h), a11_1 = lofs(rowA1, 5 + 2 * h);
    const int b0_0  = 16384 + lofs(rowB, 2 * h),     b0_1 = 16384 + lofs(rowB, 2 * h + 1);
    const int b1_0  = 16384 + lofs(rowB, 4 + 2 * h), b1_1 = 16384 + lofs(rowB, 5 + 2 * h);

    f32x16 acc0, acc1;
#pragma unroll
    for (int i = 0; i < 16; ++i) { acc0[i] = 0.f; acc1[i] = 0.f; }

    // prologue: stage K-step 0 into buf0
    GL2LDS16(gA0, lA0); GL2LDS16(gA1, lA1);
    GL2LDS16(gA2, lA2); GL2LDS16(gA3, lA3);
    GL2LDS16(gB0, lB0); GL2LDS16(gB1, lB1);
    asm volatile("s_waitcnt vmcnt(0)" ::: "memory");
    __builtin_amdgcn_s_barrier();

    for (int ks = 0; ks < 16; ++ks) {
        const int buf = ks & 1;
        if (ks < 15) {                       // stage next K-step into other buf
            const int ko = (ks + 1) * 32, bo = (buf ^ 1) * 24576;
            GL2LDS16(gA0 + ko, lA0 + bo); GL2LDS16(gA1 + ko, lA1 + bo);
            GL2LDS16(gA2 + ko, lA2 + bo); GL2LDS16(gA3 + ko, lA3 + bo);
            GL2LDS16(gB0 + ko, lB0 + bo); GL2LDS16(gB1 + ko, lB1 + bo);
        }
        const unsigned char* sb = smem + buf * 24576;
#define LD4(off) (*reinterpret_cast<const float4*>(sb + (off)))
        const f16x8 fa00 = mkfrag(LD4(a00_0), LD4(a00_1));
        const f16x8 fa01 = mkfrag(LD4(a01_0), LD4(a01_1));
        const f16x8 fa10 = mkfrag(LD4(a10_0), LD4(a10_1));
        const f16x8 fa11 = mkfrag(LD4(a11_0), LD4(a11_1));
        const f16x8 fb0  = mkfrag(LD4(b0_0),  LD4(b0_1));
        const f16x8 fb1  = mkfrag(LD4(b1_0),  LD4(b1_1));
#undef LD4
        acc0 = __builtin_amdgcn_mfma_f32_32x32x16_f16(fa00, fb0, acc0, 0, 0, 0);
        acc0 = __builtin_amdgcn_mfma_f32_32x32x16_f16(fa01, fb1, acc0, 0, 0, 0);
        acc1 = __builtin_amdgcn_mfma_f32_32x32x16_f16(fa10, fb0, acc1, 0, 0, 0);
        acc1 = __builtin_amdgcn_mfma_f32_32x32x16_f16(fa11, fb1, acc1, 0, 0, 0);
        if (ks < 15) {
            asm volatile("s_waitcnt vmcnt(0)" ::: "memory");
            __builtin_amdgcn_s_barrier();
        }
    }

    // epilogue (mapping validated R4+): D col = t, row = (reg&3)+8*(reg>>2)+4*h
    const int TK = 1 << tkshift;
    const int trow = tt * 64 + wn * 32 + r31;
    const int slice = Bi * 16 + (trow >> tkshift);
    const int t = trow & (TK - 1);
    const int nf0 = mt * 128 + wm * 64 + 4 * h;
#pragma unroll
    for (int ab = 0; ab < 2; ++ab) {
        const f32x16 acc = ab ? acc1 : acc0;
#pragma unroll
        for (int reg = 0; reg < 16; ++reg) {
            const int nf = nf0 + ab * 32 + (reg & 3) + 8 * (reg >> 2);
            Y[((size_t)(slice * 512 + nf) << tkshift) + t] = acc[reg] * C2;
        }
    }
}

// ---------------------------------------------------------------------------
// Fused score + softmax + context — R13 structure; vatt read directly
// (w = -2v folded out: a += v*r, combined sum scaled by -2 once).
// 512 blocks x 1024 threads; q-tile of 4; nh = tid>>7 splits n 8-ways.
// ---------------------------------------------------------------------------
__global__ __launch_bounds__(1024)
void score_ctx_kernel(const float* __restrict__ pqT,   // [32][512][64]
                      const float* __restrict__ pkT,   // [32][512][128]
                      const float* __restrict__ vatt,  // [512]
                      const float* __restrict__ keys,  // [32][128][512]
                      float* __restrict__ sc_out,      // [32][64][128]
                      float* __restrict__ ctx)         // [32][64][512]
{
    // bijective XCD swizzle: xcd owns 4 slices
    const int xcd = blockIdx.x & 7, ix = blockIdx.x >> 3;
    const int slice = xcd * 4 + (ix >> 4);
    const int q0    = (ix & 15) * 4;
    const int tid   = threadIdx.x;
    const int k     = tid & 127;
    const int nh    = tid >> 7;   // 0..7

    __shared__ float partial[7][4][128];              // 14KB
    __shared__ __align__(16) float scQ[4][128];       // 2KB  (q-major)
    __shared__ __align__(16) float4 ctxp[4][4][128];  // 32KB context tree
    __shared__ float wredm[8], wreds[8];

    // wave-uniform scalar bases for pq4 / v
    const int wv = __builtin_amdgcn_readfirstlane(nh);
    const float* __restrict__ pqb = pqT + ((size_t)slice * 512 + wv * 64) * 64 + q0;
    const float* __restrict__ vb  = vatt + wv * 64;
    const float* __restrict__ pkp = pkT + ((size_t)slice * 512 + wv * 64) * 128 + k;

    float a0 = 0.f, a1 = 0.f, a2 = 0.f, a3 = 0.f;
#pragma unroll 8
    for (int n = 0; n < 64; ++n) {
        const float pk = pkp[(size_t)n * 128];                          // vector (L2)
        const float4 pq = *reinterpret_cast<const float4*>(pqb + n * 64); // s_load_dwordx4
        const float v = vb[n];                                          // s_load
        const float e0 = __builtin_amdgcn_exp2f(pq.x + pk) + 1.f;
        const float e1 = __builtin_amdgcn_exp2f(pq.y + pk) + 1.f;
        const float e2 = __builtin_amdgcn_exp2f(pq.z + pk) + 1.f;
        const float e3 = __builtin_amdgcn_exp2f(pq.w + pk) + 1.f;
        a0 = fmaf(v, rcp_nr(e0), a0);                    // VALU pipe
        a1 = fmaf(v, rcp_nr(e1), a1);                    // VALU pipe
        a2 = fmaf(v, __builtin_amdgcn_rcpf(e2), a2);     // trans pipe
        a3 = fmaf(v, __builtin_amdgcn_rcpf(e3), a3);     // trans pipe
    }
    if (nh) {
        partial[nh - 1][0][k] = a0; partial[nh - 1][1][k] = a1;
        partial[nh - 1][2][k] = a2; partial[nh - 1][3][k] = a3;
    }
    __syncthreads();
    if (!nh) {
        float s0 = a0, s1 = a1, s2 = a2, s3 = a3;
#pragma unroll
        for (int p = 0; p < 7; ++p) {
            s0 += partial[p][0][k]; s1 += partial[p][1][k];
            s2 += partial[p][2][k]; s3 += partial[p][3][k];
        }
        // score = -2 * sum(v*sigma)  (+const dropped: softmax shift-invariant)
        scQ[0][k] = -2.f * s0; scQ[1][k] = -2.f * s1;
        scQ[2][k] = -2.f * s2; scQ[3][k] = -2.f * s3;
    }
    __syncthreads();

    // softmax over k=128 per q; threads < 512 active, j = nh&3
    {
        const int j = nh & 3;
        float e = 0.f;
        if (tid < 512) {
            const float orig = scQ[j][k];
            const float m0 = wave_rmax(orig);
            if ((tid & 63) == 0) wredm[tid >> 6] = m0;
            e = orig;
        }
        __syncthreads();
        if (tid < 512) {
            const float m = fmaxf(wredm[2 * j], wredm[2 * j + 1]);
            e = __builtin_amdgcn_exp2f((e - m) * LOG2E);
            const float ss = wave_rsum(e);
            if ((tid & 63) == 0) wreds[tid >> 6] = ss;
        }
        __syncthreads();
        if (tid < 512) {
            const float s = wreds[2 * j] + wreds[2 * j + 1];
            const float p = e * __builtin_amdgcn_rcpf(s);
            sc_out[((size_t)slice * 64 + q0 + j) * 128 + k] = p;
            scQ[j][k] = p;
        }
    }
    __syncthreads();

    // context: kg owns 16 k-rows; kv loaded once per 4 q's; broadcast prob reads
    const int kg = nh, n4 = k;
    float4 acc0 = {0,0,0,0}, acc1 = {0,0,0,0}, acc2 = {0,0,0,0}, acc3 = {0,0,0,0};
    const float* __restrict__ kb = keys + (size_t)slice * 65536 + (size_t)(kg * 16) * 512 + n4 * 4;
#pragma unroll
    for (int r4 = 0; r4 < 4; ++r4) {
        const float4 pv0 = *reinterpret_cast<const float4*>(&scQ[0][kg * 16 + r4 * 4]);
        const float4 pv1 = *reinterpret_cast<const float4*>(&scQ[1][kg * 16 + r4 * 4]);
        const float4 pv2 = *reinterpret_cast<const float4*>(&scQ[2][kg * 16 + r4 * 4]);
        const float4 pv3 = *reinterpret_cast<const float4*>(&scQ[3][kg * 16 + r4 * 4]);
        const float pa[4][4] = {{pv0.x, pv0.y, pv0.z, pv0.w},
                                {pv1.x, pv1.y, pv1.z, pv1.w},
                                {pv2.x, pv2.y, pv2.z, pv2.w},
                                {pv3.x, pv3.y, pv3.z, pv3.w}};
#pragma unroll
        for (int rr = 0; rr < 4; ++rr) {
            const float4 kv = *reinterpret_cast<const float4*>(kb + (size_t)(r4 * 4 + rr) * 512);
            acc0.x = fmaf(pa[0][rr], kv.x, acc0.x); acc0.y = fmaf(pa[0][rr], kv.y, acc0.y);
            acc0.z = fmaf(pa[0][rr], kv.z, acc0.z); acc0.w = fmaf(pa[0][rr], kv.w, acc0.w);
            acc1.x = fmaf(pa[1][rr], kv.x, acc1.x); acc1.y = fmaf(pa[1][rr], kv.y, acc1.y);
            acc1.z = fmaf(pa[1][rr], kv.z, acc1.z); acc1.w = fmaf(pa[1][rr], kv.w, acc1.w);
            acc2.x = fmaf(pa[2][rr], kv.x, acc2.x); acc2.y = fmaf(pa[2][rr], kv.y, acc2.y);
            acc2.z = fmaf(pa[2][rr], kv.z, acc2.z); acc2.w = fmaf(pa[2][rr], kv.w, acc2.w);
            acc3.x = fmaf(pa[3][rr], kv.x, acc3.x); acc3.y = fmaf(pa[3][rr], kv.y, acc3.y);
            acc3.z = fmaf(pa[3][rr], kv.z, acc3.z); acc3.w = fmaf(pa[3][rr], kv.w, acc3.w);
        }
    }

    // tree-combine 8 kg-groups -> kg 0, then store
    if (kg >= 4) {
        ctxp[kg - 4][0][n4] = acc0; ctxp[kg - 4][1][n4] = acc1;
        ctxp[kg - 4][2][n4] = acc2; ctxp[kg - 4][3][n4] = acc3;
    }
    __syncthreads();
    if (kg < 4) {
        const float4 o0 = ctxp[kg][0][n4], o1 = ctxp[kg][1][n4];
        const float4 o2 = ctxp[kg][2][n4], o3 = ctxp[kg][3][n4];
        acc0.x += o0.x; acc0.y += o0.y; acc0.z += o0.z; acc0.w += o0.w;
        acc1.x += o1.x; acc1.y += o1.y; acc1.z += o1.z; acc1.w += o1.w;
        acc2.x += o2.x; acc2.y += o2.y; acc2.z += o2.z; acc2.w += o2.w;
        acc3.x += o3.x; acc3.y += o3.y; acc3.z += o3.z; acc3.w += o3.w;
    }
    __syncthreads();
    if (kg == 2 || kg == 3) {
        ctxp[kg - 2][0][n4] = acc0; ctxp[kg - 2][1][n4] = acc1;
        ctxp[kg - 2][2][n4] = acc2; ctxp[kg - 2][3][n4] = acc3;
    }
    __syncthreads();
    if (kg < 2) {
        const float4 o0 = ctxp[kg][0][n4], o1 = ctxp[kg][1][n4];
        const float4 o2 = ctxp[kg][2][n4], o3 = ctxp[kg][3][n4];
        acc0.x += o0.x; acc0.y += o0.y; acc0.z += o0.z; acc0.w += o0.w;
        acc1.x += o1.x; acc1.y += o1.y; acc1.z += o1.z; acc1.w += o1.w;
        acc2.x += o2.x; acc2.y += o2.y; acc2.z += o2.z; acc2.w += o2.w;
        acc3.x += o3.x; acc3.y += o3.y; acc3.z += o3.z; acc3.w += o3.w;
    }
    __syncthreads();
    if (kg == 1) {
        ctxp[0][0][n4] = acc0; ctxp[0][1][n4] = acc1;
        ctxp[0][2][n4] = acc2; ctxp[0][3][n4] = acc3;
    }
    __syncthreads();
    if (kg == 0) {
        const float4 o0 = ctxp[0][0][n4], o1 = ctxp[0][1][n4];
        const float4 o2 = ctxp[0][2][n4], o3 = ctxp[0][3][n4];
        acc0.x += o0.x; acc0.y += o0.y; acc0.z += o0.z; acc0.w += o0.w;
        acc1.x += o1.x; acc1.y += o1.y; acc1.z += o1.z; acc1.w += o1.w;
        acc2.x += o2.x; acc2.y += o2.y; acc2.z += o2.z; acc2.w += o2.w;
        acc3.x += o3.x; acc3.y += o3.y; acc3.z += o3.z; acc3.w += o3.w;
        float* cb = ctx + ((size_t)slice * 64 + q0) * 512 + n4 * 4;
        *reinterpret_cast<float4*>(cb)             = acc0;
        *reinterpret_cast<float4*>(cb + 512)       = acc1;
        *reinterpret_cast<float4*>(cb + 2 * 512)   = acc2;
        *reinterpret_cast<float4*>(cb + 3 * 512)   = acc3;
    }
}

// ---------------------------------------------------------------------------
extern "C" void kernel_launch(void* const* d_in, const int* in_sizes, int n_in,
                              void* d_out, int out_size, void* d_ws, size_t ws_size,
                              hipStream_t stream)
{
    const float* query = (const float*)d_in[0];
    const float* keys  = (const float*)d_in[1];
    const float* Wq    = (const float*)d_in[2];
    const float* Wk    = (const float*)d_in[3];
    const float* vatt  = (const float*)d_in[4];

    float* ctx_out = (float*)d_out;
    float* sc_out  = ctx_out + (size_t)32 * 64 * 512;

    float* pqT = (float*)d_ws;                                    // 4MB
    float* pkT = pqT + (size_t)32 * 512 * 64;                     // 8MB

    proj_mfma_kernel<<<dim3(384), 256, 0, stream>>>(query, keys, Wq, Wk, pqT, pkT);
    score_ctx_kernel<<<dim3(512), 1024, 0, stream>>>(pqT, pkT, vatt, keys, sc_out, ctx_out);
}

// Round 15
// 53.893 us; speedup vs baseline: 1.0179x; 1.0179x over previous
//
#include <hip/hip_runtime.h>

// Problem dims: B=2, b=16, t_q=64, t_k=128, d=512, slices = 32
// d_out = context [32][64][512] f32 ++ scores_normalized [32][64][128] f32
// d_ws: pqT [32][512][64] (4MB) ++ pkT [32][512][128] (8MB) ++ X16 (8MB f16)
//       ++ wtab[512] (@20MB: -2*vatt)
// FINAL (R13 configuration, measured 53.9 us):
//   cvt (BW-bound) -> fp16-MFMA proj (2-phase gload_lds dbuf) ->
//   fused score+softmax+context (scalar pq/w loads, L2 pk, shift-inv softmax).

#define DEV_INLINE __device__ __forceinline__

constexpr float C2    = 2.8853900817779268f;  // 2*log2(e)
constexpr float LOG2E = 1.4426950408889634f;

typedef _Float16 f16x8 __attribute__((ext_vector_type(8)));
typedef float    f32x16 __attribute__((ext_vector_type(16)));

DEV_INLINE unsigned int pk2(float a, float b) {
    auto h = __builtin_amdgcn_cvt_pkrtz(a, b);
    return __builtin_bit_cast(unsigned int, h);
}

// Newton reciprocal: pure-VALU replacement for v_rcp_f32 (rel err ~6e-6)
DEV_INLINE float rcp_nr(float d) {
    float y = __builtin_bit_cast(float, 0x7EF311C3u - __builtin_bit_cast(unsigned int, d));
    y = y * (2.0f - d * y);
    y = y * (2.0f - d * y);
    return y;
}

#define GL2LDS16(g, l) __builtin_amdgcn_global_load_lds( \
    (const __attribute__((address_space(1))) void*)(g),  \
    (__attribute__((address_space(3))) void*)(l), 16, 0, 0)

DEV_INLINE float wave_rsum(float v) {
#pragma unroll
    for (int off = 32; off; off >>= 1) v += __shfl_xor(v, off, 64);
    return v;
}
DEV_INLINE float wave_rmax(float v) {
#pragma unroll
    for (int off = 32; off; off >>= 1) v = fmaxf(v, __shfl_xor(v, off, 64));
    return v;
}

// ---------------------------------------------------------------------------
// One-shot f32 -> f16 conversion + wtab (-2v) build (block 4096).
// ---------------------------------------------------------------------------
__global__ __launch_bounds__(256)
void cvt_f16_kernel(const float* __restrict__ query, const float* __restrict__ keys,
                    const float* __restrict__ Wq,    const float* __restrict__ Wk,
                    const float* __restrict__ vatt,
                    uint2* __restrict__ dst, float* __restrict__ wtab)
{
    if (blockIdx.x == 4096) {     // wtab: -2*v table (sumv dropped: softmax shift-inv)
        const int t = threadIdx.x;
        wtab[t] = -2.f * vatt[t]; wtab[t + 256] = -2.f * vatt[t + 256];
        return;
    }
    const int i4 = blockIdx.x * 256 + threadIdx.x;      // 0 .. 1,048,575
    const float* src; int base;
    if (i4 < 262144)      { src = query; base = 0; }
    else if (i4 < 786432) { src = keys;  base = 262144; }
    else if (i4 < 917504) { src = Wq;    base = 786432; }
    else                  { src = Wk;    base = 917504; }
    const float4 v = *reinterpret_cast<const float4*>(src + (size_t)(i4 - base) * 4);
    dst[i4] = make_uint2(pk2(v.x, v.y), pk2(v.z, v.w));
}

// ---------------------------------------------------------------------------
// fp16 MFMA projection GEMM (validated R4-R13).
// ---------------------------------------------------------------------------
__global__ __launch_bounds__(256)
void proj_mfma_kernel(const _Float16* __restrict__ X16,
                      float* __restrict__ pqT, float* __restrict__ pkT)
{
    __shared__ __align__(16) unsigned char smem[24576];   // 2 x (A 8KB + B 4KB)

    const int bid = (blockIdx.x & 7) * 48 + (blockIdx.x >> 3);

    int Bi, mt, tt, tkshift;
    const _Float16 *Wb, *Xb; float* Y;
    if (bid < 128) {      // query GEMM
        Bi = bid >> 6; mt = (bid >> 4) & 3; tt = bid & 15;
        Xb = X16 + ((size_t)Bi * 1024 + tt * 64) * 512;
        Wb = X16 + 3145728 + (size_t)Bi * 262144 + (size_t)(mt * 128) * 512;
        Y = pqT; tkshift = 6;
    } else {              // keys GEMM
        const int b2 = bid - 128;
        Bi = b2 >> 7; mt = (b2 >> 5) & 3; tt = b2 & 31;
        Xb = X16 + 1048576 + ((size_t)Bi * 2048 + tt * 64) * 512;
        Wb = X16 + 3670016 + (size_t)Bi * 262144 + (size_t)(mt * 128) * 512;
        Y = pkT; tkshift = 7;
    }
    const int tid = threadIdx.x;

    auto srcoff = [](int u) {
        const int row = u >> 2, s = (u & 3) ^ ((row >> 1) & 3);
        return (size_t)row * 512 + s * 8;
    };
    const _Float16* gA0 = Wb + srcoff(tid);
    const _Float16* gA1 = Wb + srcoff(tid + 256);
    const _Float16* gB  = Xb + srcoff(tid);
    unsigned char* const ldsA0 = smem + tid * 16;
    unsigned char* const ldsA1 = smem + 4096 + tid * 16;
    unsigned char* const ldsB  = smem + 8192 + tid * 16;

    const int wid = tid >> 6, lane = tid & 63;
    const int wm = wid >> 1, wn = wid & 1;
    const int r31 = lane & 31, h = lane >> 5;
    auto lofs = [](int row, int slot) {
        return row * 64 + ((slot ^ ((row >> 1) & 3)) * 16);
    };
    const int rowA0 = wm * 64 + r31, rowA1 = rowA0 + 32, rowB = wn * 32 + r31;
    const int a00 = lofs(rowA0, h),     a01 = lofs(rowA0, 2 + h);
    const int a10 = lofs(rowA1, h),     a11 = lofs(rowA1, 2 + h);
    const int b0  = 8192 + lofs(rowB, h), b1 = 8192 + lofs(rowB, 2 + h);

    f32x16 acc0, acc1;
#pragma unroll
    for (int i = 0; i < 16; ++i) { acc0[i] = 0.f; acc1[i] = 0.f; }

    GL2LDS16(gA0, ldsA0);
    GL2LDS16(gA1, ldsA1);
    GL2LDS16(gB,  ldsB);
    asm volatile("s_waitcnt vmcnt(0)" ::: "memory");
    __builtin_amdgcn_s_barrier();

    for (int ks = 0; ks < 16; ++ks) {
        const int buf = ks & 1;
        if (ks < 15) {
            const int ko = (ks + 1) * 32, bo = (buf ^ 1) * 12288;
            GL2LDS16(gA0 + ko, ldsA0 + bo);
            GL2LDS16(gA1 + ko, ldsA1 + bo);
            GL2LDS16(gB  + ko, ldsB  + bo);
        }
        const unsigned char* sb = smem + buf * 12288;
        const f16x8 fa00 = *reinterpret_cast<const f16x8*>(sb + a00);
        const f16x8 fa01 = *reinterpret_cast<const f16x8*>(sb + a01);
        const f16x8 fa10 = *reinterpret_cast<const f16x8*>(sb + a10);
        const f16x8 fa11 = *reinterpret_cast<const f16x8*>(sb + a11);
        const f16x8 fb0  = *reinterpret_cast<const f16x8*>(sb + b0);
        const f16x8 fb1  = *reinterpret_cast<const f16x8*>(sb + b1);
        acc0 = __builtin_amdgcn_mfma_f32_32x32x16_f16(fa00, fb0, acc0, 0, 0, 0);
        acc0 = __builtin_amdgcn_mfma_f32_32x32x16_f16(fa01, fb1, acc0, 0, 0, 0);
        acc1 = __builtin_amdgcn_mfma_f32_32x32x16_f16(fa10, fb0, acc1, 0, 0, 0);
        acc1 = __builtin_amdgcn_mfma_f32_32x32x16_f16(fa11, fb1, acc1, 0, 0, 0);
        if (ks < 15) {
            asm volatile("s_waitcnt vmcnt(0)" ::: "memory");
            __builtin_amdgcn_s_barrier();
        }
    }

    const int TK = 1 << tkshift;
    const int trow = tt * 64 + wn * 32 + r31;
    const int slice = Bi * 16 + (trow >> tkshift);
    const int t = trow & (TK - 1);
    const int nf0 = mt * 128 + wm * 64 + 4 * h;
#pragma unroll
    for (int ab = 0; ab < 2; ++ab) {
        const f32x16 acc = ab ? acc1 : acc0;
#pragma unroll
        for (int reg = 0; reg < 16; ++reg) {
            const int nf = nf0 + ab * 32 + (reg & 3) + 8 * (reg >> 2);
            Y[((size_t)(slice * 512 + nf) << tkshift) + t] = acc[reg] * C2;
        }
    }
}

// ---------------------------------------------------------------------------
// Fused score + softmax + context (best measured structure, R9/R13).
// 512 blocks x 1024 threads; q-tile of 4; nh = tid>>7 splits n 8-ways.
// Score loop: wave-uniform scalar pq/w loads, direct L2 pk, 2xNR + 2x v_rcp.
// ---------------------------------------------------------------------------
__global__ __launch_bounds__(1024)
void score_ctx_kernel(const float* __restrict__ pqT,   // [32][512][64]
                      const float* __restrict__ pkT,   // [32][512][128]
                      const float* __restrict__ wtab,  // [512] = -2v
                      const float* __restrict__ keys,  // [32][128][512]
                      float* __restrict__ sc_out,      // [32][64][128]
                      float* __restrict__ ctx)         // [32][64][512]
{
    // bijective XCD swizzle: xcd owns 4 slices
    const int xcd = blockIdx.x & 7, ix = blockIdx.x >> 3;
    const int slice = xcd * 4 + (ix >> 4);
    const int q0    = (ix & 15) * 4;
    const int tid   = threadIdx.x;
    const int k     = tid & 127;
    const int nh    = tid >> 7;   // 0..7

    __shared__ float partial[7][4][128];              // 14KB
    __shared__ __align__(16) float scQ[4][128];       // 2KB  (q-major)
    __shared__ __align__(16) float4 ctxp[4][4][128];  // 32KB context tree
    __shared__ float wredm[8], wreds[8];

    // wave-uniform scalar bases for pq4 / w
    const int wv = __builtin_amdgcn_readfirstlane(nh);
    const float* __restrict__ pqb = pqT + ((size_t)slice * 512 + wv * 64) * 64 + q0;
    const float* __restrict__ wb  = wtab + wv * 64;
    const float* __restrict__ pkp = pkT + ((size_t)slice * 512 + wv * 64) * 128 + k;

    float a0 = 0.f, a1 = 0.f, a2 = 0.f, a3 = 0.f;
#pragma unroll 8
    for (int n = 0; n < 64; ++n) {
        const float pk = pkp[(size_t)n * 128];                          // vector (L2)
        const float4 pq = *reinterpret_cast<const float4*>(pqb + n * 64); // s_load_dwordx4
        const float w = wb[n];                                          // s_load
        const float e0 = __builtin_amdgcn_exp2f(pq.x + pk) + 1.f;
        const float e1 = __builtin_amdgcn_exp2f(pq.y + pk) + 1.f;
        const float e2 = __builtin_amdgcn_exp2f(pq.z + pk) + 1.f;
        const float e3 = __builtin_amdgcn_exp2f(pq.w + pk) + 1.f;
        a0 = fmaf(w, rcp_nr(e0), a0);                    // VALU pipe
        a1 = fmaf(w, rcp_nr(e1), a1);                    // VALU pipe
        a2 = fmaf(w, __builtin_amdgcn_rcpf(e2), a2);     // trans pipe
        a3 = fmaf(w, __builtin_amdgcn_rcpf(e3), a3);     // trans pipe
    }
    if (nh) {
        partial[nh - 1][0][k] = a0; partial[nh - 1][1][k] = a1;
        partial[nh - 1][2][k] = a2; partial[nh - 1][3][k] = a3;
    }
    __syncthreads();
    if (!nh) {
        float s0 = a0, s1 = a1, s2 = a2, s3 = a3;     // sumv dropped (shift-inv)
#pragma unroll
        for (int p = 0; p < 7; ++p) {
            s0 += partial[p][0][k]; s1 += partial[p][1][k];
            s2 += partial[p][2][k]; s3 += partial[p][3][k];
        }
        scQ[0][k] = s0; scQ[1][k] = s1; scQ[2][k] = s2; scQ[3][k] = s3;
    }
    __syncthreads();

    // softmax over k=128 per q; threads < 512 active, j = nh&3
    {
        const int j = nh & 3;
        float e = 0.f;
        if (tid < 512) {
            const float orig = scQ[j][k];
            const float m0 = wave_rmax(orig);
            if ((tid & 63) == 0) wredm[tid >> 6] = m0;
            e = orig;
        }
        __syncthreads();
        if (tid < 512) {
            const float m = fmaxf(wredm[2 * j], wredm[2 * j + 1]);
            e = __builtin_amdgcn_exp2f((e - m) * LOG2E);
            const float ss = wave_rsum(e);
            if ((tid & 63) == 0) wreds[tid >> 6] = ss;
        }
        __syncthreads();
        if (tid < 512) {
            const float s = wreds[2 * j] + wreds[2 * j + 1];
            const float p = e * __builtin_amdgcn_rcpf(s);
            sc_out[((size_t)slice * 64 + q0 + j) * 128 + k] = p;
            scQ[j][k] = p;
        }
    }
    __syncthreads();

    // context: kg owns 16 k-rows; kv loaded once per 4 q's; broadcast prob reads
    const int kg = nh, n4 = k;
    float4 acc0 = {0,0,0,0}, acc1 = {0,0,0,0}, acc2 = {0,0,0,0}, acc3 = {0,0,0,0};
    const float* __restrict__ kb = keys + (size_t)slice * 65536 + (size_t)(kg * 16) * 512 + n4 * 4;
#pragma unroll
    for (int r4 = 0; r4 < 4; ++r4) {
        const float4 pv0 = *reinterpret_cast<const float4*>(&scQ[0][kg * 16 + r4 * 4]);
        const float4 pv1 = *reinterpret_cast<const float4*>(&scQ[1][kg * 16 + r4 * 4]);
        const float4 pv2 = *reinterpret_cast<const float4*>(&scQ[2][kg * 16 + r4 * 4]);
        const float4 pv3 = *reinterpret_cast<const float4*>(&scQ[3][kg * 16 + r4 * 4]);
        const float pa[4][4] = {{pv0.x, pv0.y, pv0.z, pv0.w},
                                {pv1.x, pv1.y, pv1.z, pv1.w},
                                {pv2.x, pv2.y, pv2.z, pv2.w},
                                {pv3.x, pv3.y, pv3.z, pv3.w}};
#pragma unroll
        for (int rr = 0; rr < 4; ++rr) {
            const float4 kv = *reinterpret_cast<const float4*>(kb + (size_t)(r4 * 4 + rr) * 512);
            acc0.x = fmaf(pa[0][rr], kv.x, acc0.x); acc0.y = fmaf(pa[0][rr], kv.y, acc0.y);
            acc0.z = fmaf(pa[0][rr], kv.z, acc0.z); acc0.w = fmaf(pa[0][rr], kv.w, acc0.w);
            acc1.x = fmaf(pa[1][rr], kv.x, acc1.x); acc1.y = fmaf(pa[1][rr], kv.y, acc1.y);
            acc1.z = fmaf(pa[1][rr], kv.z, acc1.z); acc1.w = fmaf(pa[1][rr], kv.w, acc1.w);
            acc2.x = fmaf(pa[2][rr], kv.x, acc2.x); acc2.y = fmaf(pa[2][rr], kv.y, acc2.y);
            acc2.z = fmaf(pa[2][rr], kv.z, acc2.z); acc2.w = fmaf(pa[2][rr], kv.w, acc2.w);
            acc3.x = fmaf(pa[3][rr], kv.x, acc3.x); acc3.y = fmaf(pa[3][rr], kv.y, acc3.y);
            acc3.z = fmaf(pa[3][rr], kv.z, acc3.z); acc3.w = fmaf(pa[3][rr], kv.w, acc3.w);
        }
    }

    // tree-combine 8 kg-groups -> kg 0, then store
    if (kg >= 4) {
        ctxp[kg - 4][0][n4] = acc0; ctxp[kg - 4][1][n4] = acc1;
        ctxp[kg - 4][2][n4] = acc2; ctxp[kg - 4][3][n4] = acc3;
    }
    __syncthreads();
    if (kg < 4) {
        const float4 o0 = ctxp[kg][0][n4], o1 = ctxp[kg][1][n4];
        const float4 o2 = ctxp[kg][2][n4], o3 = ctxp[kg][3][n4];
        acc0.x += o0.x; acc0.y += o0.y; acc0.z += o0.z; acc0.w += o0.w;
        acc1.x += o1.x; acc1.y += o1.y; acc1.z += o1.z; acc1.w += o1.w;
        acc2.x += o2.x; acc2.y += o2.y; acc2.z += o2.z; acc2.w += o2.w;
        acc3.x += o3.x; acc3.y += o3.y; acc3.z += o3.z; acc3.w += o3.w;
    }
    __syncthreads();
    if (kg == 2 || kg == 3) {
        ctxp[kg - 2][0][n4] = acc0; ctxp[kg - 2][1][n4] = acc1;
        ctxp[kg - 2][2][n4] = acc2; ctxp[kg - 2][3][n4] = acc3;
    }
    __syncthreads();
    if (kg < 2) {
        const float4 o0 = ctxp[kg][0][n4], o1 = ctxp[kg][1][n4];
        const float4 o2 = ctxp[kg][2][n4], o3 = ctxp[kg][3][n4];
        acc0.x += o0.x; acc0.y += o0.y; acc0.z += o0.z; acc0.w += o0.w;
        acc1.x += o1.x; acc1.y += o1.y; acc1.z += o1.z; acc1.w += o1.w;
        acc2.x += o2.x; acc2.y += o2.y; acc2.z += o2.z; acc2.w += o2.w;
        acc3.x += o3.x; acc3.y += o3.y; acc3.z += o3.z; acc3.w += o3.w;
    }
    __syncthreads();
    if (kg == 1) {
        ctxp[0][0][n4] = acc0; ctxp[0][1][n4] = acc1;
        ctxp[0][2][n4] = acc2; ctxp[0][3][n4] = acc3;
    }
    __syncthreads();
    if (kg == 0) {
        const float4 o0 = ctxp[0][0][n4], o1 = ctxp[0][1][n4];
        const float4 o2 = ctxp[0][2][n4], o3 = ctxp[0][3][n4];
        acc0.x += o0.x; acc0.y += o0.y; acc0.z += o0.z; acc0.w += o0.w;
        acc1.x += o1.x; acc1.y += o1.y; acc1.z += o1.z; acc1.w += o1.w;
        acc2.x += o2.x; acc2.y += o2.y; acc2.z += o2.z; acc2.w += o2.w;
        acc3.x += o3.x; acc3.y += o3.y; acc3.z += o3.z; acc3.w += o3.w;
        float* cb = ctx + ((size_t)slice * 64 + q0) * 512 + n4 * 4;
        *reinterpret_cast<float4*>(cb)             = acc0;
        *reinterpret_cast<float4*>(cb + 512)       = acc1;
        *reinterpret_cast<float4*>(cb + 2 * 512)   = acc2;
        *reinterpret_cast<float4*>(cb + 3 * 512)   = acc3;
    }
}

// ---------------------------------------------------------------------------
extern "C" void kernel_launch(void* const* d_in, const int* in_sizes, int n_in,
                              void* d_out, int out_size, void* d_ws, size_t ws_size,
                              hipStream_t stream)
{
    const float* query = (const float*)d_in[0];
    const float* keys  = (const float*)d_in[1];
    const float* Wq    = (const float*)d_in[2];
    const float* Wk    = (const float*)d_in[3];
    const float* vatt  = (const float*)d_in[4];

    float* ctx_out = (float*)d_out;
    float* sc_out  = ctx_out + (size_t)32 * 64 * 512;

    float* pqT = (float*)d_ws;                                    // 4MB
    float* pkT = pqT + (size_t)32 * 512 * 64;                     // 8MB
    _Float16* X16 = (_Float16*)((char*)d_ws + 12 * 1024 * 1024);  // 8MB f16
    float* wtab = (float*)((char*)d_ws + 20 * 1024 * 1024);       // 512 f32

    cvt_f16_kernel<<<dim3(4097), 256, 0, stream>>>(query, keys, Wq, Wk, vatt,
                                                   (uint2*)X16, wtab);
    proj_mfma_kernel<<<dim3(384), 256, 0, stream>>>(X16, pqT, pkT);
    score_ctx_kernel<<<dim3(512), 1024, 0, stream>>>(pqT, pkT, wtab, keys, sc_out, ctx_out);
}